// Round 1
// baseline (227.208 us; speedup 1.0000x reference)
//
#include <hip/hip_runtime.h>

// RandomShiftsAug: the reference's grid_sample reduces exactly to an
// integer-pixel shift with replicate clamping:
//   out[n,c,oy,ox] = x[n,c, clamp(oy+sy-pad,0,H-1), clamp(ox+sx-pad,0,W-1)]
// because ix = ((arange[ox] + sx*2/Hp + 1)*Wp - 1)/2 == ox + sx exactly.
// Pure memory-movement kernel: float4 stores (rows are 16B-aligned since
// W*4B = 336 = 21*16), 4 clamped scalar gathers per thread.

#define NN 512
#define CC 9
#define HH 84
#define WW 84

__global__ __launch_bounds__(256) void random_shift_kernel(
    const float* __restrict__ x,
    const int* __restrict__ shift,
    const int* __restrict__ pad_p,
    float* __restrict__ out)
{
    const int pad = pad_p[0];
    const int W4 = WW / 4;                       // 21
    const int total = NN * CC * HH * W4;         // 8,128,512
    int idx = blockIdx.x * blockDim.x + threadIdx.x;
    if (idx >= total) return;

    int ox4 = idx % W4;
    int t   = idx / W4;
    int oy  = t % HH;
    t      /= HH;
    int c   = t % CC;
    int n   = t / CC;

    // shift[n,0,0,0] = x-shift (width), shift[n,0,0,1] = y-shift (height)
    int sx = shift[2 * n + 0] - pad;
    int sy = shift[2 * n + 1] - pad;

    int sry = min(max(oy + sy, 0), HH - 1);
    const float* __restrict__ src =
        x + ((size_t)(n * CC + c) * HH + sry) * WW;

    int ox = ox4 * 4;
    int x0 = min(max(ox + 0 + sx, 0), WW - 1);
    int x1 = min(max(ox + 1 + sx, 0), WW - 1);
    int x2 = min(max(ox + 2 + sx, 0), WW - 1);
    int x3 = min(max(ox + 3 + sx, 0), WW - 1);

    float4 v;
    v.x = src[x0];
    v.y = src[x1];
    v.z = src[x2];
    v.w = src[x3];

    float4* __restrict__ dst =
        (float4*)(out + ((size_t)(n * CC + c) * HH + oy) * WW + ox);
    *dst = v;
}

extern "C" void kernel_launch(void* const* d_in, const int* in_sizes, int n_in,
                              void* d_out, int out_size, void* d_ws, size_t ws_size,
                              hipStream_t stream)
{
    const float* x     = (const float*)d_in[0];
    const int*   shift = (const int*)d_in[1];
    const int*   pad   = (const int*)d_in[2];
    float*       out   = (float*)d_out;

    const int total  = NN * CC * HH * (WW / 4);
    const int block  = 256;
    const int grid   = (total + block - 1) / block;
    random_shift_kernel<<<grid, block, 0, stream>>>(x, shift, pad, out);
}

// Round 3
// 221.895 us; speedup vs baseline: 1.0239x; 1.0239x over previous
//
#include <hip/hip_runtime.h>

// RandomShiftsAug: the reference's grid_sample reduces exactly to an
// integer-pixel shift with replicate clamping:
//   out[n,c,oy,ox] = x[n,c, clamp(oy+sy-pad,0,H-1), clamp(ox+sx-pad,0,W-1)]
// (ix = ((arange[ox] + sx*2/Hp + 1)*Wp - 1)/2 == ox + sx exactly; bilinear
// weights degenerate to {1,0}; float noise ~1e-5 << 0.108 threshold).
//
// R3: one 16B load per lane at the clamped window start (4B-aligned
// global unaligned dwordx4), branchless cndmask fix-up for edge lanes
// (|sx|<=4 so only ox4 in {0,20} can clamp). Nontemporal 16B store via
// ext_vector_type (HIP float4 struct is rejected by the builtin).

#define NN 512
#define CC 9
#define HH 84
#define WW 84

typedef float f4u __attribute__((ext_vector_type(4), aligned(4)));   // load, 4B-aligned
typedef float f4a __attribute__((ext_vector_type(4)));               // store, 16B-aligned

__global__ __launch_bounds__(256) void random_shift_kernel(
    const float* __restrict__ x,
    const int* __restrict__ shift,
    const int* __restrict__ pad_p,
    float* __restrict__ out)
{
    const int pad = pad_p[0];
    const int W4 = WW / 4;                       // 21
    const int total = NN * CC * HH * W4;         // 8,128,512
    int idx = blockIdx.x * blockDim.x + threadIdx.x;
    if (idx >= total) return;

    int ox4 = idx % W4;
    int t   = idx / W4;
    int oy  = t % HH;
    t      /= HH;
    int c   = t % CC;
    int n   = t / CC;

    // shift[n,0,0,0] = x-shift (width), shift[n,0,0,1] = y-shift (height)
    int sx = shift[2 * n + 0] - pad;
    int sy = shift[2 * n + 1] - pad;

    int sry = min(max(oy + sy, 0), HH - 1);
    const float* __restrict__ src =
        x + ((size_t)(n * CC + c) * HH + sry) * WW;

    int ox = ox4 * 4;
    int s  = ox + sx;                 // window start in source row
    int a  = min(max(s, 0), WW - 4);  // clamped window start (interior: a==s)

    f4u w = *(const f4u*)(src + a);   // one 16B load, 4B-aligned

    // element j wants src[clamp(s+j,0,W-1)] which lies in [a, a+3]
    int k0 = min(max(s + 0, 0), WW - 1) - a;
    int k1 = min(max(s + 1, 0), WW - 1) - a;
    int k2 = min(max(s + 2, 0), WW - 1) - a;
    int k3 = min(max(s + 3, 0), WW - 1) - a;

    f4a v;
    v.x = k0 == 0 ? w.x : (k0 == 1 ? w.y : (k0 == 2 ? w.z : w.w));
    v.y = k1 == 1 ? w.y : (k1 == 0 ? w.x : (k1 == 2 ? w.z : w.w));
    v.z = k2 == 2 ? w.z : (k2 == 1 ? w.y : (k2 == 3 ? w.w : w.x));
    v.w = k3 == 3 ? w.w : (k3 == 2 ? w.z : (k3 == 1 ? w.y : w.x));

    f4a* __restrict__ dst =
        (f4a*)(out + ((size_t)(n * CC + c) * HH + oy) * WW + ox);
    __builtin_nontemporal_store(v, dst);
}

extern "C" void kernel_launch(void* const* d_in, const int* in_sizes, int n_in,
                              void* d_out, int out_size, void* d_ws, size_t ws_size,
                              hipStream_t stream)
{
    const float* x     = (const float*)d_in[0];
    const int*   shift = (const int*)d_in[1];
    const int*   pad   = (const int*)d_in[2];
    float*       out   = (float*)d_out;

    const int total  = NN * CC * HH * (WW / 4);
    const int block  = 256;
    const int grid   = (total + block - 1) / block;
    random_shift_kernel<<<grid, block, 0, stream>>>(x, shift, pad, out);
}